// Round 11
// baseline (241.130 us; speedup 1.0000x reference)
//
#include <hip/hip_runtime.h>
#include <hip/hip_fp16.h>

// Fused Conv3d(3->16, 3x3x3, VALID) + bias + channel softmax + maxpool(4,4,4)/4.
// x: [512,3,16,32,32] f32, w: [16,3,3,3,3] f32, b: [16] f32 -> out [512,16,3,7,7] f32
//
// R11 = R10 (MFMA implicit GEMM, 16x16x32_f16, fp32 accum) + bank-conflict fix:
//  - LDS x-tile strides (dwords): lh=17, ld=103, cin=619 -> tap-group bank
//    phase = (11cin+7kd+17kh)%32, 27 distinct spread values (was 2 phases).
//  - K-permutation (free): tap-groups assigned to gather slots so each
//    ds_read_b64's 4 lane-group windows sit ~8 banks apart. All 5 pad groups
//    collected in slot (v3,second) -> that read skipped (A-frag is zero).
//  - parity-duplicated copy kept (odd-wp lanes read dup32, same banks, 2-way free).

typedef _Float16 half8 __attribute__((ext_vector_type(8)));
typedef float f32x4 __attribute__((ext_vector_type(4)));
union H8 { int4 i; half8 h; };

// PERM[2v+delta][g] = tap-group G = cin*9+kd*3+kh assigned to that slot (-1 = pad).
__device__ __constant__ int PERM[8][4] = {
  { 0,  5,  8,  4}, { 2, 16, 12, 17},
  {13,  9, 14, 10}, {24, 11, 25, 21},
  {26,  6, 18,  7}, { 3, 22, 20, 23},
  {19,  1, 15, -1}, {-1, -1, -1, -1}};

__device__ __forceinline__ int sel4(int g, int a, int b, int c, int d) {
  int ab = (g & 1) ? b : a;
  int cd = (g & 1) ? d : c;
  return (g & 2) ? cd : ab;
}

// A-frags: wsA[v][lane] = 8 halves A[c=lane&15][k=32v+8g+j], j0-3 <- PERM[2v][g],
// j4-7 <- PERM[2v+1][g]; within a group k -> kw = j&3 (kw==3 or G<0 -> zero).
__global__ void wtrans(const float* __restrict__ w, int4* __restrict__ wsA) {
  int t = threadIdx.x;            // 256 threads: v = t>>6, lane = t&63
  int v = t >> 6, l = t & 63;
  int c = l & 15, g = l >> 4;
  unsigned hh[8];
  for (int j = 0; j < 8; ++j) {
    int G = PERM[2 * v + (j >> 2)][g];
    int kw = j & 3;
    float val = (G >= 0 && kw < 3) ? w[c * 81 + 3 * G + kw] : 0.0f;
    hh[j] = (unsigned)__half_as_ushort(__float2half(val));
  }
  int4 o;
  o.x = (int)(hh[0] | (hh[1] << 16));
  o.y = (int)(hh[2] | (hh[3] << 16));
  o.z = (int)(hh[4] | (hh[5] << 16));
  o.w = (int)(hh[6] | (hh[7] << 16));
  wsA[v * 64 + l] = o;
}

__global__ __launch_bounds__(128) void conv_sm_pool(
    const float* __restrict__ x, const int4* __restrict__ wsA,
    const float* __restrict__ b, float* __restrict__ out) {
  __shared__ int xs32[1856];    // x tile, strides (dw): lh 17, ld 103, cin 619
  __shared__ int dup32[1856];   // dup[i] = halves(2i+1, 2i+2)
  __shared__ float pool2[896];  // [wv*4+dh][pw][c]

  const int tid = threadIdx.x;
  const int blk = blockIdx.x;
  const int n = blk / 21, rr = blk % 21, pd = rr / 7, ph = rr % 7;

  // ---- stage x tile as fp16 pairs into padded layout ----
  const float* xb = x + ((size_t)n * 3 * 16 * 32 * 32)
                  + (size_t)(4 * pd) * 1024 + (size_t)(4 * ph) * 32;
  for (int i = tid; i < 1728; i += 128) {
    int lw2 = i & 15;
    int rest = i >> 4;          // cin*36 + ld*6 + lh
    int lh = rest % 6, rest2 = rest / 6, ld = rest2 % 6, cin = rest2 / 6;
    float2 v = *reinterpret_cast<const float2*>(
        &xb[((cin * 16 + ld) * 32 + lh) * 32 + lw2 * 2]);
    __half2 h2 = __float22half2_rn(v);
    xs32[cin * 619 + ld * 103 + lh * 17 + lw2] = *reinterpret_cast<int*>(&h2);
  }
  __syncthreads();
  // ---- shifted duplicate for odd-parity lanes ----
  for (int i = tid; i < 1856; i += 128) {
    int cur = xs32[i];
    int nxt = (i < 1855) ? xs32[i + 1] : 0;
    dup32[i] = (int)(((unsigned)cur >> 16) | ((unsigned)nxt << 16));
  }
  __syncthreads();

  const int lane = tid & 63, wv = tid >> 6;
  const int l15 = lane & 15, g = lane >> 4;
  const int par = l15 & 1;
  const int* bas = par ? dup32 : xs32;

  // A-frags (weights)
  H8 wa[4];
#pragma unroll
  for (int v = 0; v < 4; ++v) wa[v].i = wsA[v * 64 + lane];

  // tap-group dword offsets per slot (match PERM; pads -> 0)
  int TH0[4], TH1[3];
  TH0[0] = sel4(g,    0,  137,  240,  120);   // G 0,5,8,4
  TH1[0] = sel4(g,   34,  842,  722,  859);   // G 2,16,12,17
  TH0[1] = sel4(g,  739,  619,  756,  636);   // G 13,9,14,10
  TH1[1] = sel4(g, 1444,  653, 1461, 1341);   // G 24,11,25,21
  TH0[2] = sel4(g, 1478,  206, 1238,  223);   // G 26,6,18,7
  TH1[2] = sel4(g,  103, 1358, 1272, 1375);   // G 3,22,20,23
  TH0[3] = sel4(g, 1255,   17,  825,    0);   // G 19,1,15,pad

  // position dword offsets per N-tile (new strides)
  int PH[14];
#pragma unroll
  for (int tl = 0; tl < 14; ++tl) {
    int m0 = (wv * 14 + tl) * 16;
    int dd = m0 / 112;
    int r112 = m0 % 112;
    int dhc = r112 / 28, r28 = r112 % 28;
    int bump = (r28 + l15) >= 28 ? 1 : 0;
    PH[tl] = dd * 103 + (dhc + bump) * 17 + ((r28 + l15 - 28 * bump - par) >> 1);
  }

  // acc init with bias (row = channel = 4g+q)
  f32x4 acc[14];
  float4 b4 = *reinterpret_cast<const float4*>(b + 4 * g);
  f32x4 binit;
  binit[0] = b4.x; binit[1] = b4.y; binit[2] = b4.z; binit[3] = b4.w;
#pragma unroll
  for (int tl = 0; tl < 14; ++tl) acc[tl] = binit;

  // ---- main: 4 K-windows x 14 N-tiles ----
#pragma unroll
  for (int v = 0; v < 4; ++v) {
#pragma unroll
    for (int tl = 0; tl < 14; ++tl) {
      int o0 = PH[tl] + TH0[v];
      H8 bf;
      bf.i.x = bas[o0];
      bf.i.y = bas[o0 + 1];
      if (v < 3) {
        int o1 = PH[tl] + TH1[v];
        bf.i.z = bas[o1];
        bf.i.w = bas[o1 + 1];
      } else {
        bf.i.z = 0;             // slot (v3, second) = all pad groups, A is zero
        bf.i.w = 0;
      }
      acc[tl] = __builtin_amdgcn_mfma_f32_16x16x32_f16(wa[v].h, bf.h, acc[tl], 0, 0, 0);
    }
  }

  // ---- epilogue: softmax over channels (cross lane-group), pool ----
#pragma unroll
  for (int tp = 0; tp < 7; ++tp) {
    float pm[4];
#pragma unroll
    for (int hf = 0; hf < 2; ++hf) {
      int tl = tp + 7 * hf;     // tiles tp, tp+7: same (dh,wp), dd differs by 2
      float e[4];
#pragma unroll
      for (int q = 0; q < 4; ++q) e[q] = __expf(acc[tl][q]);
      float s = (e[0] + e[1]) + (e[2] + e[3]);
      s += __shfl_xor(s, 16, 64);
      s += __shfl_xor(s, 32, 64);
      float rs = __builtin_amdgcn_rcpf(s);
      if (hf == 0) {
#pragma unroll
        for (int q = 0; q < 4; ++q) pm[q] = e[q] * rs;
      } else {
#pragma unroll
        for (int q = 0; q < 4; ++q) pm[q] = fmaxf(pm[q], e[q] * rs);
      }
    }
    // wp-quad reduce (l15 quads never straddle the h-bump: r28 % 4 == 0)
#pragma unroll
    for (int q = 0; q < 4; ++q) {
      pm[q] = fmaxf(pm[q], __shfl_xor(pm[q], 1, 64));
      pm[q] = fmaxf(pm[q], __shfl_xor(pm[q], 2, 64));
    }
    if ((l15 & 3) == 0) {
      int m0 = (wv * 14 + tp) * 16;
      int r112 = m0 % 112;
      int dhc = r112 / 28, r28 = r112 % 28;
      int bump = (r28 + l15) >= 28 ? 1 : 0;
      int dh = dhc + bump;
      int pw = (r28 + l15 - 28 * bump) >> 2;
      float4 val = {pm[0], pm[1], pm[2], pm[3]};
      *reinterpret_cast<float4*>(&pool2[(((wv * 4 + dh) * 7 + pw) << 4) + 4 * g]) = val;
    }
  }
  __syncthreads();

  if (tid < 112) {
    int c = tid / 7, pw = tid % 7;
    float m = pool2[(pw << 4) + c];
#pragma unroll
    for (int s = 1; s < 8; ++s)
      m = fmaxf(m, pool2[((s * 7 + pw) << 4) + c]);
    out[(((size_t)n * 16 + c) * 3 + pd) * 49 + (size_t)ph * 7 + pw] = m;
  }
}

extern "C" void kernel_launch(void* const* d_in, const int* in_sizes, int n_in,
                              void* d_out, int out_size, void* d_ws, size_t ws_size,
                              hipStream_t stream) {
  const float* x = (const float*)d_in[0];
  const float* w = (const float*)d_in[1];
  const float* b = (const float*)d_in[2];
  float* out = (float*)d_out;
  int4* wsA = (int4*)d_ws;   // 4 * 64 * 16 B = 4096 B
  (void)in_sizes; (void)n_in; (void)out_size; (void)ws_size;
  hipLaunchKernelGGL(wtrans, dim3(1), dim3(256), 0, stream, w, wsA);
  hipLaunchKernelGGL(conv_sm_pool, dim3(512 * 3 * 7), dim3(128), 0, stream,
                     x, wsA, b, out);
}